// Round 3
// baseline (6305.007 us; speedup 1.0000x reference)
//
#include <hip/hip_runtime.h>
#include <stdint.h>

// Seq2seq GRU encoder + greedy GRU decoder, single persistent cooperative kernel.
// R3 changes vs R2:
//  - Contention-free grid barrier: per-block epoch flag stores (no shared-line
//    RMW fan-in), every block's wave 0 polls all 256 flags (4 loads/lane).
//  - NTHR 512 (8 waves/CU): phase-B thread = (row, k-quarter) -> 2x MLP on the
//    L3 lint stream; GRU dots split across wave pairs (k-halves), LDS combine.

#define HID 1024
#define SRC_LEN 256
#define MAX_LEN 128
#define VOC 32000
#define EOS_TOK 2u

#define NBLK 256
#define NTHR 512
#define RPB 125            // vocab rows per block = 32000/256

// ---- workspace layout (bytes) ----
#define WS_FLAG   1024     // u32[256] per-block epoch flags
#define WS_GSUM   2048     // u64[128] fixed-point softmax sums
#define WS_GKEY   3072     // u64[128] argmax keys
#define WS_HB     4096     // float[2][1024] double-buffered h
#define WS_EXP    12288    // float[32000] exp(logit)   (same-block only)
#define WS_ZERO   12288    // bytes to memset each call (flags+gsum+gkey+hb)
#define WS_LINT   141312   // u64[256 blocks][256 k4][128 r] transposed bf16 lin_w
#define WS_NEED   (141312ull + 256ull * 256ull * 128ull * 8ull)

#define A_SCOPE __HIP_MEMORY_SCOPE_AGENT

__device__ inline unsigned ld_a32(const unsigned* p) {
  return __hip_atomic_load((unsigned*)p, __ATOMIC_RELAXED, A_SCOPE);
}
__device__ inline void st_a32(unsigned* p, unsigned v) {
  __hip_atomic_store(p, v, __ATOMIC_RELAXED, A_SCOPE);
}
__device__ inline unsigned long long ld_a64(const unsigned long long* p) {
  return __hip_atomic_load((unsigned long long*)p, __ATOMIC_RELAXED, A_SCOPE);
}
__device__ inline void st_af(float* p, float v) {
  __hip_atomic_store(p, v, __ATOMIC_RELAXED, A_SCOPE);
}

__device__ inline unsigned short f2bf(float f) {
  unsigned u = __float_as_uint(f);
  unsigned r = ((u >> 16) & 1u) + 0x7FFFu;   // round-to-nearest-even
  return (unsigned short)((u + r) >> 16);
}
__device__ inline float bflo(unsigned u) { return __uint_as_float(u << 16); }
__device__ inline float bfhi(unsigned u) { return __uint_as_float(u & 0xFFFF0000u); }
__device__ inline float sigm(float x) { return 1.0f / (1.0f + __expf(-x)); }

// Contention-free grid barrier: store own epoch flag, wave 0 polls all 256.
// Each wave drains its own vmem (s_waitcnt 0) before the first __syncthreads,
// so flag>=ep implies that block's agent stores reached the coherence point.
__device__ inline void grid_bar(char* ws, unsigned* ep_) {
  __builtin_amdgcn_s_waitcnt(0);
  __syncthreads();
  const unsigned ep = ++(*ep_);
  const int tid = threadIdx.x;
  unsigned* fl = (unsigned*)(ws + WS_FLAG);
  if (tid == 0) st_a32(fl + blockIdx.x, ep);
  if (tid < 64) {
    for (;;) {
      const bool ok = (ld_a32(fl + tid)       >= ep) &
                      (ld_a32(fl + tid + 64)  >= ep) &
                      (ld_a32(fl + tid + 128) >= ep) &
                      (ld_a32(fl + tid + 192) >= ep);
      if (__all(ok ? 1 : 0)) break;
      __builtin_amdgcn_s_sleep(1);
    }
  }
  __syncthreads();
}

// stage 4KB h vector from ws into LDS via coherent u64 loads (512 threads)
__device__ inline void load_h_lds(float* dst, const float* src, int tid) {
  ((unsigned long long*)dst)[tid] = ld_a64((const unsigned long long*)src + tid);
}

// partial GRU dots for unit ju over k-half kh (512 elements), all-lane results
__device__ inline void gru_partial(const float* __restrict__ wih,
                                   const float* __restrict__ whh,
                                   int ju, int kh, int lane,
                                   const float* __restrict__ sx,
                                   const float* __restrict__ sh,
                                   float* __restrict__ p) {
  const size_t ro = (size_t)ju * HID + ((size_t)kh << 9);
  const size_t gs = (size_t)HID * HID;
  const float* a0 = wih + ro;
  const float* a1 = wih + ro + gs;
  const float* a2 = wih + ro + 2 * gs;
  const float* c0 = whh + ro;
  const float* c1 = whh + ro + gs;
  const float* c2 = whh + ro + 2 * gs;
  const float* xs = sx + (kh << 9);
  const float* hs = sh + (kh << 9);
  float ai0 = 0.f, ai1 = 0.f, ai2 = 0.f, ah0 = 0.f, ah1 = 0.f, ah2 = 0.f;
#pragma unroll
  for (int i = 0; i < 4; ++i) {
    const int e = 2 * lane + 128 * i;
    const float2 xv = *(const float2*)(xs + e);
    const float2 hv = *(const float2*)(hs + e);
    float2 w;
    w = *(const float2*)(a0 + e); ai0 += w.x * xv.x + w.y * xv.y;
    w = *(const float2*)(a1 + e); ai1 += w.x * xv.x + w.y * xv.y;
    w = *(const float2*)(a2 + e); ai2 += w.x * xv.x + w.y * xv.y;
    w = *(const float2*)(c0 + e); ah0 += w.x * hv.x + w.y * hv.y;
    w = *(const float2*)(c1 + e); ah1 += w.x * hv.x + w.y * hv.y;
    w = *(const float2*)(c2 + e); ah2 += w.x * hv.x + w.y * hv.y;
  }
#pragma unroll
  for (int off = 32; off; off >>= 1) {
    ai0 += __shfl_xor(ai0, off); ai1 += __shfl_xor(ai1, off); ai2 += __shfl_xor(ai2, off);
    ah0 += __shfl_xor(ah0, off); ah1 += __shfl_xor(ah1, off); ah2 += __shfl_xor(ah2, off);
  }
  p[0] = ai0; p[1] = ai1; p[2] = ai2; p[3] = ah0; p[4] = ah1; p[5] = ah2;
}

__global__ void __launch_bounds__(NTHR)
seq2seq_kernel(const int* __restrict__ X,
               const float* __restrict__ enc_emb,
               const float* __restrict__ enc_wih, const float* __restrict__ enc_whh,
               const float* __restrict__ enc_bih, const float* __restrict__ enc_bhh,
               const float* __restrict__ dec_emb,
               const float* __restrict__ dec_wih, const float* __restrict__ dec_whh,
               const float* __restrict__ dec_bih, const float* __restrict__ dec_bhh,
               const float* __restrict__ lin_w, const float* __restrict__ lin_b,
               float* __restrict__ out, char* __restrict__ ws, int useBf) {
  __shared__ float sx[HID];
  __shared__ float sh[HID];
  __shared__ float spart[NTHR];
  __shared__ float slog[128];
  __shared__ float redS[8];
  __shared__ float sg[8][6];
  __shared__ float sbmax;
  __shared__ unsigned long long sball[2];

  const int b = blockIdx.x, tid = threadIdx.x;
  const int q = tid >> 6, lane = tid & 63;
  const int ju = 4 * b + (q & 3);   // GRU unit for this wave
  const int kh = q >> 2;            // k-half for this wave
  const int vbase = b * RPB;
  unsigned ep = 0;

  unsigned long long* gsum = (unsigned long long*)(ws + WS_GSUM);
  unsigned long long* gkey = (unsigned long long*)(ws + WS_GKEY);
  float* hb = (float*)(ws + WS_HB);
  float* expb = (float*)(ws + WS_EXP);
  unsigned long long* lint = (unsigned long long*)(ws + WS_LINT);
  float* probs = out + (MAX_LEN + 1);

  // per-wave biases for unit ju (gates r,z,n stacked at 0,H,2H)
  const float ebi0 = enc_bih[ju], ebi1 = enc_bih[HID + ju], ebi2 = enc_bih[2 * HID + ju];
  const float ebh0 = enc_bhh[ju], ebh1 = enc_bhh[HID + ju], ebh2 = enc_bhh[2 * HID + ju];
  const float dbi0 = dec_bih[ju], dbi1 = dec_bih[HID + ju], dbi2 = dec_bih[2 * HID + ju];
  const float dbh0 = dec_bhh[ju], dbh1 = dec_bhh[HID + ju], dbh2 = dec_bhh[2 * HID + ju];

  if (b == 0 && tid == 0) out[0] = 1.0f;  // SOS

  // ---- P0: block-local transposed bf16 copy of this block's 125 lin_w rows ----
  // layout: lint[b][k4][r] u64 = 4 bf16 (k = 4*k4..4*k4+3) of row vbase+r.
  if (useBf) {
    unsigned long long* dst = lint + ((size_t)b << 15);
    for (int i = 0; i < 64; ++i) {
      const int g = i * NTHR + tid;          // 0..32767
      const int r = g & 127, k4 = g >> 7;    // k4 0..255
      unsigned long long w = 0ull;
      if (r < RPB) {
        const float4 f = *(const float4*)(lin_w + (size_t)(vbase + r) * HID + 4 * k4);
        w = (unsigned long long)f2bf(f.x)
          | ((unsigned long long)f2bf(f.y) << 16)
          | ((unsigned long long)f2bf(f.z) << 32)
          | ((unsigned long long)f2bf(f.w) << 48);
      }
      dst[g] = w;
    }
  }
  grid_bar(ws, &ep);

  // ---- encoder: 256 sequential GRU steps ----
  for (int t = 0; t < SRC_LEN; ++t) {
    const float* hcur = hb + (t & 1) * HID;
    float* hnext = hb + ((t + 1) & 1) * HID;
    const int tokt = X[t];
    ((float2*)sx)[tid] = ((const float2*)(enc_emb + (size_t)tokt * HID))[tid];
    load_h_lds(sh, hcur, tid);
    __syncthreads();
    float p6[6];
    gru_partial(enc_wih, enc_whh, ju, kh, lane, sx, sh, p6);
    if (lane == 0) {
#pragma unroll
      for (int i = 0; i < 6; ++i) sg[q][i] = p6[i];
    }
    __syncthreads();
    if (q < 4 && lane == 0) {
      const float rr = sigm(sg[q][0] + sg[q + 4][0] + ebi0 + sg[q][3] + sg[q + 4][3] + ebh0);
      const float zz = sigm(sg[q][1] + sg[q + 4][1] + ebi1 + sg[q][4] + sg[q + 4][4] + ebh1);
      const float nn = tanhf(sg[q][2] + sg[q + 4][2] + ebi2 + rr * (sg[q][5] + sg[q + 4][5] + ebh2));
      st_af(&hnext[ju], (1.f - zz) * nn + zz * sh[ju]);
    }
    grid_bar(ws, &ep);
  }

  // ---- greedy decoder ----
  unsigned tok = 1u;   // SOS
  bool done = false;

  for (int t = 0; t <= MAX_LEN; ++t) {
    if (t > 0) {
      const unsigned long long key = ld_a64(&gkey[t - 1]);
      const unsigned nxt = 0xFFFFFFFFu - (unsigned)(key & 0xFFFFFFFFull);
      if (b == 0 && tid == 0) out[t] = done ? (float)EOS_TOK : (float)nxt;
      if (tid < RPB) {
        float p = 0.f;
        if (!done) {
          const unsigned long long sraw = ld_a64(&gsum[t - 1]);
          const double s = (double)sraw * (1.0 / 16777216.0);
          p = expb[vbase + tid] * (float)(1.0 / s);
        }
        probs[(size_t)(t - 1) * VOC + vbase + tid] = p;
      }
      if (!done) tok = nxt;
      done = done || (nxt == EOS_TOK);
    }
    if (t == MAX_LEN) break;
    if (done) {
      for (int s = t; s < MAX_LEN; ++s) {
        if (tid < RPB) probs[(size_t)s * VOC + vbase + tid] = 0.f;
        if (b == 0 && tid == 0) out[s + 1] = (float)EOS_TOK;
      }
      break;
    }

    // ---- phase A: GRU cell on x = relu(dec_emb[tok]) ----
    const float* hcur = hb + (t & 1) * HID;
    float* hnext = hb + ((t + 1) & 1) * HID;
    {
      float2 f = ((const float2*)(dec_emb + (size_t)tok * HID))[tid];
      f.x = fmaxf(f.x, 0.f); f.y = fmaxf(f.y, 0.f);
      ((float2*)sx)[tid] = f;
    }
    load_h_lds(sh, hcur, tid);
    __syncthreads();
    float p6[6];
    gru_partial(dec_wih, dec_whh, ju, kh, lane, sx, sh, p6);
    if (lane == 0) {
#pragma unroll
      for (int i = 0; i < 6; ++i) sg[q][i] = p6[i];
    }
    __syncthreads();
    if (q < 4 && lane == 0) {
      const float rr = sigm(sg[q][0] + sg[q + 4][0] + dbi0 + sg[q][3] + sg[q + 4][3] + dbh0);
      const float zz = sigm(sg[q][1] + sg[q + 4][1] + dbi1 + sg[q][4] + sg[q + 4][4] + dbh1);
      const float nn = tanhf(sg[q][2] + sg[q + 4][2] + dbi2 + rr * (sg[q][5] + sg[q + 4][5] + dbh2));
      st_af(&hnext[ju], (1.f - zz) * nn + zz * sh[ju]);
    }
    grid_bar(ws, &ep);   // S1: h_new visible everywhere

    // ---- phase B: logits for this block's 125 vocab rows ----
    load_h_lds(sh, hnext, tid);
    if (tid < 128) slog[tid] = -1e30f;
    if (tid < 8) redS[tid] = 0.f;
    __syncthreads();

    if (useBf) {
      // thread = (row r, k-quarter kq); per-wave: uniform k addr (LDS broadcast),
      // 64 consecutive rows per wave (512B coalesced u64 stream from L3/L2)
      const int r = tid & 127, kq = tid >> 7;
      const unsigned long long* wp = lint + ((size_t)b << 15)
                                   + ((size_t)kq << 13) + (size_t)r;
      const float* hp = sh + (kq << 8);
      float acc0 = 0.f, acc1 = 0.f;
#pragma unroll 16
      for (int k4 = 0; k4 < 64; ++k4) {
        const unsigned long long w = wp[(size_t)k4 << 7];
        const float4 hv = *(const float4*)(hp + (k4 << 2));
        const unsigned lo = (unsigned)w, hi = (unsigned)(w >> 32);
        const float s = bflo(lo) * hv.x + bfhi(lo) * hv.y
                      + bflo(hi) * hv.z + bfhi(hi) * hv.w;
        if (k4 & 1) acc1 += s; else acc0 += s;
      }
      spart[tid] = acc0 + acc1;
      __syncthreads();
      if (tid < 128) {
        float e = 0.f;
        if (tid < RPB) {
          const float logit = spart[tid] + spart[tid + 128] + spart[tid + 256]
                            + spart[tid + 384] + lin_b[vbase + tid];
          e = __expf(logit);
          expb[vbase + tid] = e;
          slog[tid] = logit;
        }
        float s = e;
#pragma unroll
        for (int off = 32; off; off >>= 1) s += __shfl_xor(s, off);
        if (lane == 0) redS[q] = s;
      }
      __syncthreads();
    } else {
      // fallback: f32 row-per-wave from lin_w
      float psum = 0.f;
      for (int v = vbase + q; v < vbase + RPB; v += 8) {
        const float* wr = lin_w + (size_t)v * HID;
        float acc = 0.f;
#pragma unroll
        for (int i = 0; i < 4; ++i) {
          const float4 f = *(const float4*)(wr + 4 * lane + 256 * i);
          const float4 hv = *(const float4*)(sh + 4 * lane + 256 * i);
          acc += f.x * hv.x + f.y * hv.y + f.z * hv.z + f.w * hv.w;
        }
#pragma unroll
        for (int off = 32; off; off >>= 1) acc += __shfl_xor(acc, off);
        if (lane == 0) {
          const float logit = acc + lin_b[v];
          const float e = __expf(logit);
          expb[v] = e;
          psum += e;
          slog[v - vbase] = logit;
        }
      }
      if (lane == 0) redS[q] = psum;
      __syncthreads();
    }

    // block-local max of approx logits
    if (q == 0) {
      float m = fmaxf(slog[lane], slog[lane + 64]);
#pragma unroll
      for (int off = 32; off; off >>= 1) m = fmaxf(m, __shfl_xor(m, off));
      if (lane == 0) sbmax = m;
    }
    __syncthreads();
    if (tid < 128) {
      const bool cand = (tid < RPB) && (slog[tid] >= sbmax - 2e-3f);
      const unsigned long long bal = __ballot(cand);
      if (lane == 0) sball[q] = bal;
    }
    __syncthreads();
    // exact-f32 re-check of candidate rows -> global argmax key
    {
      unsigned long long m0 = sball[0], m1 = sball[1];
      unsigned long long bestk = 0ull;
      int c = 0;
      while (m0 | m1) {
        int r;
        if (m0) { r = __ffsll(m0) - 1; m0 &= m0 - 1; }
        else    { r = 64 + __ffsll(m1) - 1; m1 &= m1 - 1; }
        if ((c & 7) == q) {
          const int v = vbase + r;
          const float* wr = lin_w + (size_t)v * HID;
          float acc = 0.f;
#pragma unroll
          for (int i = 0; i < 4; ++i) {
            const float4 f = *(const float4*)(wr + 4 * lane + 256 * i);
            const float4 hv = *(const float4*)(sh + 4 * lane + 256 * i);
            acc += f.x * hv.x + f.y * hv.y + f.z * hv.z + f.w * hv.w;
          }
#pragma unroll
          for (int off = 32; off; off >>= 1) acc += __shfl_xor(acc, off);
          const float logit = acc + lin_b[v];
          const unsigned u = __float_as_uint(logit);
          const unsigned s = (u & 0x80000000u) ? ~u : (u | 0x80000000u);
          const unsigned long long k =
              ((unsigned long long)s << 32) | (unsigned long long)(0xFFFFFFFFu - (unsigned)v);
          if (k > bestk) bestk = k;
        }
        ++c;
      }
      if (lane == 0 && bestk) atomicMax(&gkey[t], bestk);
    }
    if (tid == 0) {
      const float st = redS[0] + redS[1] + redS[2] + redS[3]
                     + redS[4] + redS[5] + redS[6] + redS[7];
      atomicAdd(&gsum[t], (unsigned long long)((double)st * 16777216.0));
    }
    grid_bar(ws, &ep);   // S2: argmax key + sum globally visible
  }
}

extern "C" void kernel_launch(void* const* d_in, const int* in_sizes, int n_in,
                              void* d_out, int out_size, void* d_ws, size_t ws_size,
                              hipStream_t stream) {
  const int* X = (const int*)d_in[0];
  const float* enc_emb = (const float*)d_in[1];
  const float* enc_wih = (const float*)d_in[2];
  const float* enc_whh = (const float*)d_in[3];
  const float* enc_bih = (const float*)d_in[4];
  const float* enc_bhh = (const float*)d_in[5];
  const float* dec_emb = (const float*)d_in[6];
  const float* dec_wih = (const float*)d_in[7];
  const float* dec_whh = (const float*)d_in[8];
  const float* dec_bih = (const float*)d_in[9];
  const float* dec_bhh = (const float*)d_in[10];
  const float* lin_w = (const float*)d_in[11];
  const float* lin_b = (const float*)d_in[12];
  float* out = (float*)d_out;
  char* ws = (char*)d_ws;
  int useBf = (ws_size >= (size_t)WS_NEED) ? 1 : 0;

  hipMemsetAsync(d_ws, 0, WS_ZERO, stream);
  void* args[] = { &X, &enc_emb, &enc_wih, &enc_whh, &enc_bih, &enc_bhh,
                   &dec_emb, &dec_wih, &dec_whh, &dec_bih, &dec_bhh,
                   &lin_w, &lin_b, &out, &ws, &useBf };
  hipLaunchCooperativeKernel((void*)seq2seq_kernel, dim3(NBLK), dim3(NTHR),
                             args, 0, stream);
}